// Round 3
// baseline (201.805 us; speedup 1.0000x reference)
//
#include <hip/hip_runtime.h>
#include <math.h>

#define SB 1024
#define NS 64
#define BT 256
#define HID 64
#define HEAD 128
#define IN_DIM 42

// d_ws layout (floats): [0..4095] G = W3*W3^T (64x64), [4096..4159] g = W3*b3,
//                       [4160..8255] W2t (W2t[j][i] = W2[i][j])
#define WS_G   0
#define WS_g   4096
#define WS_W2T 4160

__device__ __forceinline__ void load_pose(const float* __restrict__ p,
                                          float& lx, float& ly, float& lz,
                                          float& dx, float& dy, float& dz) {
    float2 r0 = *(const float2*)(p + 2);
    float2 r1 = *(const float2*)(p + 6);
    float2 r2 = *(const float2*)(p + 10);
    dx = r0.x; lx = r0.y;
    dy = r1.x; ly = r1.y;
    dz = r2.x; lz = r2.y;
}

// rowop(row, value) over the 42 PE features: [loc3 | sin/cos x6 freqs | dir3]
template <class F>
__device__ __forceinline__ void pe_apply(F&& rowop, float lx, float ly, float lz,
                                         float dx, float dy, float dz) {
    rowop(0, lx); rowop(1, ly); rowop(2, lz);
    #pragma unroll
    for (int c = 0; c < 3; ++c) {
        float lc = (c == 0) ? lx : ((c == 1) ? ly : lz);
        float sv, cv;
        __sincosf(1.5f * lc, &sv, &cv);
        #pragma unroll
        for (int i = 0; i < 6; ++i) {
            rowop(3 + 6 * i + c, sv);
            rowop(6 + 6 * i + c, cv);
            float ns = 2.f * sv * cv, nc = cv * cv - sv * sv;
            sv = ns; cv = nc;
        }
    }
    rowop(39, dx); rowop(40, dy); rowop(41, dz);
}

// ---------------- kernel 1: precompute G, g, W2t into d_ws ----------------
__global__ __launch_bounds__(256) void precompute_kernel(
    const float* __restrict__ W2, const float* __restrict__ W3,
    const float* __restrict__ b3, float* __restrict__ ws)
{
    __shared__ float W3t[HEAD][HID];   // W3t[d][j] = W3[j*128+d], 32 KB
    const int tid = threadIdx.x;
    for (int i = tid; i < HID * HEAD / 4; i += 256) {
        float4 v = ((const float4*)W3)[i];
        int j = i >> 5, d0 = (i & 31) * 4;
        W3t[d0 + 0][j] = v.x;
        W3t[d0 + 1][j] = v.y;
        W3t[d0 + 2][j] = v.z;
        W3t[d0 + 3][j] = v.w;
    }
    __syncthreads();

    const int k = tid & 63, rr = tid >> 6;
    const int r0 = blockIdx.x * 8 + rr;       // rows r0 and r0+4
    float acc0 = 0.f, acc1 = 0.f;
    for (int d = 0; d < HEAD; ++d) {
        float wk = W3t[d][k];
        acc0 = fmaf(W3t[d][r0], wk, acc0);
        acc1 = fmaf(W3t[d][r0 + 4], wk, acc1);
    }
    ws[WS_G + r0 * 64 + k]       = acc0;
    ws[WS_G + (r0 + 4) * 64 + k] = acc1;

    if (blockIdx.x == 0) {
        if (tid < 64) {
            float gacc = 0.f;
            for (int d = 0; d < HEAD; ++d) gacc = fmaf(W3t[d][tid], b3[d], gacc);
            ws[WS_g + tid] = gacc;
        }
        for (int idx = tid; idx < HID * HID; idx += 256) {
            int j = idx >> 6, i = idx & 63;
            ws[WS_W2T + idx] = W2[i * 64 + j];     // W2t[j][i]
        }
    }
}

// ---------------- kernel 2: main fused kernel ----------------
__global__ __launch_bounds__(256, 3) void cam_weighter_kernel(
    const float* __restrict__ input_poses,   // (SB,NS,4,4)
    const float* __restrict__ target_poses,  // (SB,BT,4,4)
    const float* __restrict__ W1, const float* __restrict__ b1,
    const float* __restrict__ W2, const float* __restrict__ b2,
    const float* __restrict__ ws,            // G | g | W2t
    float* __restrict__ out)                 // (SB,NS,BT)
{
    __shared__ float h1l[HID][NS];   // 16 KB
    __shared__ float h2l[HID][NS];   // 16 KB
    __shared__ float zkl[HID][NS];   // 16 KB
    __shared__ float ckl[NS];

    const int tid = threadIdx.x;
    const int s   = blockIdx.x;
    const int k    = tid & 63;
    // wave-uniform part index, forced scalar so weight-segment addrs take the s_load path
    const int part = __builtin_amdgcn_readfirstlane(tid >> 6);
    const int i0   = part * 16;

    const float* Gm  = ws + WS_G;
    const float* gm  = ws + WS_g;
    const float* W2t = ws + WS_W2T;

    // ================= keys =================
    {
        float lx, ly, lz, dx, dy, dz;
        load_pose(&input_poses[((size_t)s * NS + k) * 16], lx, ly, lz, dx, dy, dz);

        float a[16];
        #pragma unroll
        for (int t = 0; t < 16; ++t) a[t] = b1[i0 + t];
        pe_apply([&](int row, float v) {
            const float* w = &W1[row * 64 + i0];
            #pragma unroll
            for (int t = 0; t < 16; ++t) a[t] = fmaf(v, w[t], a[t]);
        }, lx, ly, lz, dx, dy, dz);
        #pragma unroll
        for (int t = 0; t < 16; ++t) h1l[i0 + t][k] = fmaxf(a[t], 0.f);
        __syncthreads();

        #pragma unroll
        for (int t = 0; t < 16; ++t) a[t] = b2[i0 + t];
        #pragma unroll 8
        for (int j = 0; j < HID; ++j) {
            float hv = h1l[j][k];                  // lane-contiguous b32
            const float* w = &W2[j * 64 + i0];     // uniform -> s_load
            #pragma unroll
            for (int t = 0; t < 16; ++t) a[t] = fmaf(hv, w[t], a[t]);
        }
        #pragma unroll
        for (int t = 0; t < 16; ++t) h2l[i0 + t][k] = fmaxf(a[t], 0.f);
        __syncthreads();

        #pragma unroll
        for (int t = 0; t < 16; ++t) a[t] = 0.f;
        float ck = 0.f;
        #pragma unroll 8
        for (int j = 0; j < HID; ++j) {
            float hv = h2l[j][k];
            const float* Gr = &Gm[j * 64 + i0];    // G row segment (symmetric)
            #pragma unroll
            for (int t = 0; t < 16; ++t) a[t] = fmaf(hv, Gr[t], a[t]);
            if (part == 0) ck = fmaf(hv, gm[j], ck);
        }
        #pragma unroll
        for (int t = 0; t < 16; ++t) zkl[i0 + t][k] = a[t];
        if (part == 0) ckl[k] = ck;
        __syncthreads();
    }

    // ================= queries =================
    {
        const int q = tid;
        float lx, ly, lz, dx, dy, dz;
        load_pose(&target_poses[((size_t)s * BT + q) * 16], lx, ly, lz, dx, dy, dz);

        float h1[HID];
        #pragma unroll
        for (int i = 0; i < HID; ++i) h1[i] = b1[i];
        pe_apply([&](int row, float v) {
            const float* w = &W1[row * 64];        // fully uniform -> s_load
            #pragma unroll
            for (int i = 0; i < HID; ++i) h1[i] = fmaf(v, w[i], h1[i]);
        }, lx, ly, lz, dx, dy, dz);
        #pragma unroll
        for (int i = 0; i < HID; ++i) h1[i] = fmaxf(h1[i], 0.f);

        float sc[NS];
        #pragma unroll
        for (int t = 0; t < 16; ++t) {
            float4 c = ((const float4*)ckl)[t];    // LDS broadcast, one-off
            sc[4*t] = c.x; sc[4*t+1] = c.y; sc[4*t+2] = c.z; sc[4*t+3] = c.w;
        }

        // fused layer2 + score: h2_j produced then immediately consumed
        #pragma unroll 2
        for (int j = 0; j < HID; ++j) {
            const float* w = &W2t[j * 64];         // uniform -> s_load
            float p0 = (j == 0) ? b2[0] : b2[j], p1 = 0.f, p2 = 0.f, p3 = 0.f;
            p0 = b2[j];
            #pragma unroll
            for (int i = 0; i < HID; i += 4) {     // 4-way split accumulator
                p0 = fmaf(h1[i],     w[i],     p0);
                p1 = fmaf(h1[i + 1], w[i + 1], p1);
                p2 = fmaf(h1[i + 2], w[i + 2], p2);
                p3 = fmaf(h1[i + 3], w[i + 3], p3);
            }
            float h2j = fmaxf((p0 + p1) + (p2 + p3), 0.f);
            const float4* z4 = (const float4*)&zkl[j][0];  // LDS broadcast
            #pragma unroll
            for (int t = 0; t < 16; ++t) {
                float4 z = z4[t];
                sc[4*t]   = fmaf(h2j, z.x, sc[4*t]);
                sc[4*t+1] = fmaf(h2j, z.y, sc[4*t+1]);
                sc[4*t+2] = fmaf(h2j, z.z, sc[4*t+2]);
                sc[4*t+3] = fmaf(h2j, z.w, sc[4*t+3]);
            }
        }

        // softmax over 64 keys (scale folded after max-subtract)
        const float scale = 0.08838834764831845f;  // 1/sqrt(128)
        float m0 = sc[0], m1 = sc[1];
        #pragma unroll
        for (int kk = 2; kk < NS; kk += 2) { m0 = fmaxf(m0, sc[kk]); m1 = fmaxf(m1, sc[kk + 1]); }
        const float m = fmaxf(m0, m1);
        float s0 = 0.f, s1 = 0.f;
        #pragma unroll
        for (int kk = 0; kk < NS; kk += 2) {
            sc[kk]     = __expf((sc[kk]     - m) * scale);
            sc[kk + 1] = __expf((sc[kk + 1] - m) * scale);
            s0 += sc[kk]; s1 += sc[kk + 1];
        }
        const float inv = 1.f / (s0 + s1);
        float* obase = out + (size_t)s * NS * BT + q;
        #pragma unroll
        for (int kk = 0; kk < NS; ++kk)
            obase[(size_t)kk * BT] = sc[kk] * inv;  // lanes = q contiguous
    }
}

extern "C" void kernel_launch(void* const* d_in, const int* in_sizes, int n_in,
                              void* d_out, int out_size, void* d_ws, size_t ws_size,
                              hipStream_t stream) {
    const float* input_poses  = (const float*)d_in[0];
    const float* target_poses = (const float*)d_in[1];
    const float* W1 = (const float*)d_in[2];
    const float* b1 = (const float*)d_in[3];
    const float* W2 = (const float*)d_in[4];
    const float* b2 = (const float*)d_in[5];
    const float* W3 = (const float*)d_in[6];
    const float* b3 = (const float*)d_in[7];
    float* out = (float*)d_out;
    float* ws  = (float*)d_ws;   // needs 8256 floats = 33 KB

    precompute_kernel<<<dim3(8), dim3(256), 0, stream>>>(W2, W3, b3, ws);
    cam_weighter_kernel<<<dim3(SB), dim3(256), 0, stream>>>(
        input_poses, target_poses, W1, b1, W2, b2, ws, out);
}